// Round 13
// baseline (59.605 us; speedup 1.0000x reference)
//
#include <hip/hip_runtime.h>
#include <hip/hip_bf16.h>

typedef __attribute__((ext_vector_type(8))) __bf16 bf16x8;
typedef __attribute__((ext_vector_type(4))) float f32x4;

#define SEQ   4096
#define HDIM  64
#define BKT   64
#define STRIP 4
#define SLOTB 8192   // bytes per LDS slot (64 x 64 bf16)

__device__ __forceinline__ unsigned f2bf_u(float f) {
    unsigned u = __float_as_uint(f);
    u += 0x7FFFu + ((u >> 16) & 1u);
    return u >> 16;
}
__device__ __forceinline__ unsigned pk2(float a, float b) {
    return f2bf_u(a) | (f2bf_u(b) << 16);
}
__device__ __forceinline__ int swzV(int row) {
    return ((row & 7) ^ ((row >> 3) & 7)) << 4;
}

// 4x4 bf16 shuffle transpose of one float4 (lane holds V[kb+g][4m..4m+3]),
// writes V^T[4m+g][kb..kb+3] into slot at slotbyte (64-wide rows, swzV).
__device__ __forceinline__ void vtrans_write(char* sVb, int slotbyte, int kl,
                                             f32x4 f, int g, int m) {
    const unsigned P0 = pk2(f[0], f[1]);
    const unsigned P1 = pk2(f[2], f[3]);
    const unsigned own  = (g < 2) ? P0 : P1;
    const unsigned send = (g < 2) ? P1 : P0;
    const unsigned R = __shfl_xor(send, 32);
    const unsigned T = __shfl_xor(own, 16);
    const unsigned U = __shfl_xor(R, 16);
    const unsigned A0 = (g < 2) ? own : R;
    const unsigned A1 = (g < 2) ? T : U;
    const unsigned A2 = (g < 2) ? R : own;
    const unsigned A3 = (g < 2) ? U : T;
    const int sdx = g & 1;
    const unsigned k0 = sdx ? A1 : A0, k1 = sdx ? A0 : A1;
    const unsigned k2 = sdx ? A3 : A2, k3 = sdx ? A2 : A3;
    const unsigned G0 = sdx ? ((k0 >> 16) | (k1 & 0xFFFF0000u)) : ((k0 & 0xFFFFu) | (k1 << 16));
    const unsigned G1 = sdx ? ((k2 >> 16) | (k3 & 0xFFFF0000u)) : ((k2 & 0xFFFFu) | (k3 << 16));
    const int er = m * 4 + g;
    const int byte = slotbyte + ((er * 128 + kl * 2) ^ swzV(er));
    uint2 p; p.x = G0; p.y = G1;
    *reinterpret_cast<uint2*>(sVb + byte) = p;
}

__global__ void __launch_bounds__(256, 4) local_attn_kernel(
    const float* __restrict__ q, const float* __restrict__ k,
    const float* __restrict__ v, float* __restrict__ out)
{
    // 2-slot rings by bucket parity: slot s holds bucket b (b&1==s).
    __shared__ __align__(16) unsigned short sK[2 * 64 * 64];   // K  [64 k][64 e] per slot
    __shared__ __align__(16) unsigned short sVt[2 * 64 * 64];  // V^T[64 e][64 k] per slot

    const int tid = threadIdx.x;
    const int bid = blockIdx.x;
    // XCD-aware bijective swizzle (1024 = 8 * 128)
    const int lg = (bid & 7) * 128 + (bid >> 3);
    const int bh = lg >> 4;
    const int strip = lg & 15;
    const int b0 = strip * STRIP;
    const int base = bh * SEQ * HDIM;

    const int lane = tid & 63;
    const int wid  = tid >> 6;
    const int g = lane >> 4, m = lane & 15;
    const int g4 = g * 4;
    const int qbase = wid * 16;
    const int qb = qbase + m;

    char* const sKb = reinterpret_cast<char*>(sK);
    char* const sVb = reinterpret_cast<char*>(sVt);

    const float scale = 0.125f * 1.44269504f;   // 64^-0.5 * log2(e)
    bf16x8 bq[2];

    // ================= prologue: buckets b0-1 (slot 1) + b0 (slot 0) ================
    {
        const int fix0 = (strip == 0) ? (BKT * HDIM) : 0;   // masked rows: any finite data
        const int win0 = base + (b0 - 1) * BKT * HDIM;
        f32x4 kreg[8], vreg[8], qreg[4];
        #pragma unroll
        for (int i = 0; i < 8; ++i) {
            const float* p = k + win0 + ((i < 4) ? fix0 : 0) + i * 1024 + tid * 4;
            asm volatile("global_load_dwordx4 %0, %1, off" : "=v"(kreg[i]) : "v"(p) : "memory");
        }
        #pragma unroll
        for (int i = 0; i < 8; ++i) {
            const int kb = i * 16 + wid * 4;
            const float* p = v + win0 + ((i < 4) ? fix0 : 0) + (kb + g) * HDIM + m * 4;
            asm volatile("global_load_dwordx4 %0, %1, off" : "=v"(vreg[i]) : "v"(p) : "memory");
        }
        const int qoff0 = base + b0 * BKT * HDIM;
        #pragma unroll
        for (int h = 0; h < 2; ++h) {
            const float* qp = q + qoff0 + qb * HDIM + h * 32 + g * 8;
            asm volatile("global_load_dwordx4 %0, %1, off" : "=v"(qreg[2 * h]) : "v"(qp) : "memory");
            asm volatile("global_load_dwordx4 %0, %1, off" : "=v"(qreg[2 * h + 1]) : "v"(qp + 4) : "memory");
        }
        asm volatile("s_waitcnt vmcnt(12)" ::: "memory");
        __builtin_amdgcn_sched_barrier(0);
        #pragma unroll
        for (int i = 0; i < 8; ++i) {
            const int flat = i * 1024 + tid * 4;
            const int lr = (flat >> 6) & 63, col = flat & 63;
            uint2 p;
            p.x = pk2(kreg[i][0], kreg[i][1]);
            p.y = pk2(kreg[i][2], kreg[i][3]);
            const int byte = ((i < 4) ? SLOTB : 0) + ((lr * 128 + col * 2) ^ ((lr & 7) << 4));
            *reinterpret_cast<uint2*>(sKb + byte) = p;
        }
        asm volatile("s_waitcnt vmcnt(4)" ::: "memory");
        __builtin_amdgcn_sched_barrier(0);
        #pragma unroll
        for (int i = 0; i < 8; ++i) {
            const int kl = (i * 16 + wid * 4) & 63;
            vtrans_write(sVb, (i < 4) ? SLOTB : 0, kl, vreg[i], g, m);
        }
        asm volatile("s_waitcnt vmcnt(0)" ::: "memory");
        __builtin_amdgcn_sched_barrier(0);
        #pragma unroll
        for (int h = 0; h < 2; ++h) {
            uint4 u;
            u.x = pk2(qreg[2 * h][0] * scale, qreg[2 * h][1] * scale);
            u.y = pk2(qreg[2 * h][2] * scale, qreg[2 * h][3] * scale);
            u.z = pk2(qreg[2 * h + 1][0] * scale, qreg[2 * h + 1][1] * scale);
            u.w = pk2(qreg[2 * h + 1][2] * scale, qreg[2 * h + 1][3] * scale);
            bq[h] = __builtin_bit_cast(bf16x8, u);
        }
        __syncthreads();
    }

    // ================= main loop: compute bucket j, prefetch j+1 ====================
    #pragma unroll
    for (int j = 0; j < STRIP; ++j) {
        const int qoffj = base + (b0 + j) * BKT * HDIM;
        const int spre = ((j & 1) ^ 1) * SLOTB;   // bucket j-1 (and dest for j+1)
        const int scur = (j & 1) * SLOTB;         // bucket j

        // ---- issue next bucket's 12 loads (pinned in flight across compute) ----
        f32x4 kn[4], vn[4], qn[4];
        if (j < STRIP - 1) {
            const int noff = qoffj + BKT * HDIM;
            #pragma unroll
            for (int i = 0; i < 4; ++i) {
                const float* p = k + noff + i * 1024 + tid * 4;
                asm volatile("global_load_dwordx4 %0, %1, off" : "=v"(kn[i]) : "v"(p) : "memory");
            }
            #pragma unroll
            for (int i = 0; i < 4; ++i) {
                const int kbl = i * 16 + wid * 4;
                const float* p = v + noff + (kbl + g) * HDIM + m * 4;
                asm volatile("global_load_dwordx4 %0, %1, off" : "=v"(vn[i]) : "v"(p) : "memory");
            }
            #pragma unroll
            for (int h = 0; h < 2; ++h) {
                const float* qp = q + noff + qb * HDIM + h * 32 + g * 8;
                asm volatile("global_load_dwordx4 %0, %1, off" : "=v"(qn[2 * h]) : "v"(qp) : "memory");
                asm volatile("global_load_dwordx4 %0, %1, off" : "=v"(qn[2 * h + 1]) : "v"(qp + 4) : "memory");
            }
        }

        // ---- S^T = K * Q^T ----
        f32x4 acc[8];
        #pragma unroll
        for (int c = 0; c < 8; ++c) acc[c] = (f32x4){0.f, 0.f, 0.f, 0.f};
        __builtin_amdgcn_s_setprio(1);
        #pragma unroll
        for (int c = 0; c < 8; ++c) {
            const int lr = (c & 3) * 16 + m;
            const int sb = (c < 4) ? spre : scur;
            #pragma unroll
            for (int h = 0; h < 2; ++h) {
                const int byte = sb + ((lr * 128 + h * 64 + g * 16) ^ ((m & 7) << 4));
                const bf16x8 ak = *reinterpret_cast<const bf16x8*>(sKb + byte);
                acc[c] = __builtin_amdgcn_mfma_f32_16x16x32_bf16(ak, bq[h], acc[c], 0, 0, 0);
            }
        }
        __builtin_amdgcn_s_setprio(0);

        // ---- mask + exact softmax (exp2 domain) ----
        const bool dead_prev = (strip == 0 && j == 0);
        float mx = -3e38f;
        #pragma unroll
        for (int c = 0; c < 8; ++c) {
            #pragma unroll
            for (int r = 0; r < 4; ++r) {
                const int kk = c * 16 + g4 + r;
                const bool dead = (c >= 4) ? (kk - 64 > qb) : dead_prev;
                const float s = dead ? -1e30f : acc[c][r];
                acc[c][r] = s;
                mx = fmaxf(mx, s);
            }
        }
        mx = fmaxf(mx, __shfl_xor(mx, 16));
        mx = fmaxf(mx, __shfl_xor(mx, 32));
        float sum = 0.f;
        uint2 pb[8];
        #pragma unroll
        for (int c = 0; c < 8; ++c) {
            const float p0 = __builtin_amdgcn_exp2f(acc[c][0] - mx);
            const float p1 = __builtin_amdgcn_exp2f(acc[c][1] - mx);
            const float p2 = __builtin_amdgcn_exp2f(acc[c][2] - mx);
            const float p3 = __builtin_amdgcn_exp2f(acc[c][3] - mx);
            sum += (p0 + p1) + (p2 + p3);
            pb[c].x = pk2(p0, p1);
            pb[c].y = pk2(p2, p3);
        }
        sum += __shfl_xor(sum, 16);
        sum += __shfl_xor(sum, 32);
        const float rl = 1.0f / sum;

        // ---- P redistribution via shuffles ----
        const int l0 = m + ((g & 1) << 5);
        const int l1 = l0 + 16;
        const bool hi2 = (g >> 1) != 0;
        bf16x8 bp[4];
        #pragma unroll
        for (int kt = 0; kt < 4; ++kt) {
            const unsigned a0x = __shfl(pb[2 * kt].x, l0),     a0y = __shfl(pb[2 * kt].y, l0);
            const unsigned a1x = __shfl(pb[2 * kt + 1].x, l0), a1y = __shfl(pb[2 * kt + 1].y, l0);
            const unsigned b0x = __shfl(pb[2 * kt].x, l1),     b0y = __shfl(pb[2 * kt].y, l1);
            const unsigned b1x = __shfl(pb[2 * kt + 1].x, l1), b1y = __shfl(pb[2 * kt + 1].y, l1);
            uint4 u;
            u.x = hi2 ? a1x : a0x;
            u.y = hi2 ? a1y : a0y;
            u.z = hi2 ? b1x : b0x;
            u.w = hi2 ? b1y : b0y;
            bp[kt] = __builtin_bit_cast(bf16x8, u);
        }

        // ---- O^T = V^T * P^T ----
        f32x4 oacc[4];
        #pragma unroll
        for (int et = 0; et < 4; ++et) oacc[et] = (f32x4){0.f, 0.f, 0.f, 0.f};
        __builtin_amdgcn_s_setprio(1);
        #pragma unroll
        for (int et = 0; et < 4; ++et) {
            const int row = et * 16 + m;
            #pragma unroll
            for (int kt = 0; kt < 4; ++kt) {
                const int sb = (kt < 2) ? spre : scur;
                const int kl = (kt & 1) * 32 + g * 8;
                const int byte = sb + ((row * 128 + kl * 2) ^ swzV(row));
                const bf16x8 av = *reinterpret_cast<const bf16x8*>(sVb + byte);
                oacc[et] = __builtin_amdgcn_mfma_f32_16x16x32_bf16(av, bp[kt], oacc[et], 0, 0, 0);
            }
        }
        __builtin_amdgcn_s_setprio(0);

        // ---- store bucket j's output ----
        #pragma unroll
        for (int et = 0; et < 4; ++et) {
            f32x4 o = oacc[et];
            o[0] *= rl; o[1] *= rl; o[2] *= rl; o[3] *= rl;
            *reinterpret_cast<float4*>(out + qoffj + qb * HDIM + et * 16 + g4) =
                *reinterpret_cast<float4*>(&o);
        }

        // ---- stage bucket j+1 into slot spre ----
        if (j < STRIP - 1) {
            __syncthreads();   // all waves done reading slot spre
            // 12 loads retired; the 4 stores above may still be outstanding
            asm volatile("s_waitcnt vmcnt(4)" ::: "memory");
            __builtin_amdgcn_sched_barrier(0);
            #pragma unroll
            for (int i = 0; i < 4; ++i) {
                const int flat = i * 1024 + tid * 4;
                const int lr = flat >> 6, col = flat & 63;
                uint2 p;
                p.x = pk2(kn[i][0], kn[i][1]);
                p.y = pk2(kn[i][2], kn[i][3]);
                const int byte = spre + ((lr * 128 + col * 2) ^ ((lr & 7) << 4));
                *reinterpret_cast<uint2*>(sKb + byte) = p;
            }
            #pragma unroll
            for (int i = 0; i < 4; ++i) {
                const int kbl = i * 16 + wid * 4;
                vtrans_write(sVb, spre, kbl, vn[i], g, m);
            }
            #pragma unroll
            for (int h = 0; h < 2; ++h) {
                uint4 u;
                u.x = pk2(qn[2 * h][0] * scale, qn[2 * h][1] * scale);
                u.y = pk2(qn[2 * h][2] * scale, qn[2 * h][3] * scale);
                u.z = pk2(qn[2 * h + 1][0] * scale, qn[2 * h + 1][1] * scale);
                u.w = pk2(qn[2 * h + 1][2] * scale, qn[2 * h + 1][3] * scale);
                bq[h] = __builtin_bit_cast(bf16x8, u);
            }
            __syncthreads();   // new slot contents visible
        }
    }
}

extern "C" void kernel_launch(void* const* d_in, const int* in_sizes, int n_in,
                              void* d_out, int out_size, void* d_ws, size_t ws_size,
                              hipStream_t stream) {
    const float* q = (const float*)d_in[0];
    const float* k = (const float*)d_in[1];
    const float* v = (const float*)d_in[2];
    float* out = (float*)d_out;
    const int bh = in_sizes[0] / (SEQ * HDIM);            // 64
    const int nblocks = bh * (SEQ / BKT / STRIP);         // 1024
    hipLaunchKernelGGL(local_attn_kernel, dim3(nblocks), dim3(256), 0, stream,
                       q, k, v, out);
}

// Round 15
// 44.832 us; speedup vs baseline: 1.3295x; 1.3295x over previous
//
#include <hip/hip_runtime.h>
#include <hip/hip_bf16.h>

typedef __attribute__((ext_vector_type(8))) __bf16 bf16x8;
typedef __attribute__((ext_vector_type(2))) __bf16 bf16x2;
typedef __attribute__((ext_vector_type(4))) float f32x4;

#define SEQ   4096
#define HDIM  64
#define BKT   64

// f32 pair -> packed bf16x2 (RNE). Plain casts let the compiler emit
// v_cvt_pk_bf16_f32 (1 VALU) instead of the ~7-op bit-twiddle. [m240]
__device__ __forceinline__ unsigned pk2(float a, float b) {
    bf16x2 t;
    t[0] = (__bf16)a;
    t[1] = (__bf16)b;
    return __builtin_bit_cast(unsigned, t);
}
// sVt swizzle: conflict-free for write rows er=4m+g AND read rows et*16+m
__device__ __forceinline__ int swzV(int row) {
    return ((row & 7) ^ ((row >> 3) & 7)) << 4;
}

__global__ void __launch_bounds__(256, 4) local_attn_kernel(
    const float* __restrict__ q, const float* __restrict__ k,
    const float* __restrict__ v, float* __restrict__ out)
{
    __shared__ __align__(16) unsigned short sK[128 * 64];   // K window bf16 [128 k][64 e]
    __shared__ __align__(16) unsigned short sVt[64 * 128];  // V^T bf16 [64 e][128 k]

    const int tid = threadIdx.x;
    const int bid0 = blockIdx.x;
    // XCD-aware bijective swizzle (4096 = 8 * 512 exact)
    const int lg = (bid0 & 7) * 512 + (bid0 >> 3);
    const int bh = lg >> 6;
    const int bucket = lg & 63;

    const int qoff = (bh * SEQ + bucket * BKT) * HDIM;
    const int koff = qoff - BKT * HDIM;
    // bucket 0: backward-window rows are fully masked -> read own bucket (no branch)
    const int fix0 = (bucket == 0) ? (BKT * HDIM) : 0;

    const int lane = tid & 63;
    const int wid  = tid >> 6;
    const int g = lane >> 4, m = lane & 15;
    const int g4 = g * 4;
    const int qbase = wid * 16;

    char* const sKb = reinterpret_cast<char*>(sK);
    char* const sVb = reinterpret_cast<char*>(sVt);

    // ========== Phase A: pin ALL 20 loads in flight via inline asm =================
    f32x4 kreg[8], vreg[8], qreg[4];
    #pragma unroll
    for (int i = 0; i < 8; ++i) {
        const float* p = k + koff + ((i < 4) ? fix0 : 0) + i * 1024 + tid * 4;
        asm volatile("global_load_dwordx4 %0, %1, off"
                     : "=v"(kreg[i]) : "v"(p) : "memory");
    }
    #pragma unroll
    for (int i = 0; i < 8; ++i) {
        const int kb = i * 16 + wid * 4;
        const float* p = v + koff + ((i < 4) ? fix0 : 0) + (kb + g) * HDIM + m * 4;
        asm volatile("global_load_dwordx4 %0, %1, off"
                     : "=v"(vreg[i]) : "v"(p) : "memory");
    }
    #pragma unroll
    for (int h = 0; h < 2; ++h) {
        const float* qp = q + qoff + (qbase + m) * HDIM + h * 32 + g * 8;
        asm volatile("global_load_dwordx4 %0, %1, off"
                     : "=v"(qreg[2 * h]) : "v"(qp) : "memory");
        asm volatile("global_load_dwordx4 %0, %1, off"
                     : "=v"(qreg[2 * h + 1]) : "v"(qp + 4) : "memory");
    }

    // ========== K ready (oldest 8 retired) -> convert + ds_write ===================
    asm volatile("s_waitcnt vmcnt(12)" ::: "memory");
    __builtin_amdgcn_sched_barrier(0);
    #pragma unroll
    for (int i = 0; i < 8; ++i) {
        const int flat = i * 1024 + tid * 4;
        const int row = flat >> 6, col = flat & 63;
        uint2 p;
        p.x = pk2(kreg[i][0], kreg[i][1]);
        p.y = pk2(kreg[i][2], kreg[i][3]);
        const int byte = (row * 128 + col * 2) ^ ((row & 7) << 4);
        *reinterpret_cast<uint2*>(sKb + byte) = p;
    }

    // ========== V ready -> in-register 4x4 shuffle transpose + ds_write ============
    asm volatile("s_waitcnt vmcnt(4)" ::: "memory");
    __builtin_amdgcn_sched_barrier(0);
    // hoisted lane-dependent constants for the transpose merges
    const int sdx = g & 1;
    const unsigned selG = sdx ? 0x03020706u : 0x05040100u;  // v_perm selector
    #pragma unroll
    for (int i = 0; i < 8; ++i) {
        const int kb = i * 16 + wid * 4;
        const f32x4 f = vreg[i];
        const unsigned P0 = pk2(f[0], f[1]);
        const unsigned P1 = pk2(f[2], f[3]);
        const unsigned own  = (g < 2) ? P0 : P1;
        const unsigned send = (g < 2) ? P1 : P0;
        const unsigned R = __shfl_xor(send, 32);
        const unsigned T = __shfl_xor(own, 16);
        const unsigned U = __shfl_xor(R, 16);
        const unsigned A0 = (g < 2) ? own : R;
        const unsigned A1 = (g < 2) ? T : U;
        const unsigned A2 = (g < 2) ? R : own;
        const unsigned A3 = (g < 2) ? U : T;
        // G0 = halves of (A0,A1) by parity; G1 = halves of (A2,A3)
        const unsigned G0 = __builtin_amdgcn_perm(A1, A0, selG);
        const unsigned G1 = __builtin_amdgcn_perm(A3, A2, selG);
        const int er = m * 4 + g;
        const int byte = (er * 256 + kb * 2) ^ swzV(er);
        uint2 p; p.x = G0; p.y = G1;
        *reinterpret_cast<uint2*>(sVb + byte) = p;
    }

    // ========== Q ready -> fragments (scale includes log2e) ========================
    asm volatile("s_waitcnt vmcnt(0)" ::: "memory");
    __builtin_amdgcn_sched_barrier(0);
    const float scale = 0.125f * 1.44269504f;
    bf16x8 bq[2];
    #pragma unroll
    for (int h = 0; h < 2; ++h) {
        uint4 u;
        u.x = pk2(qreg[2 * h][0] * scale, qreg[2 * h][1] * scale);
        u.y = pk2(qreg[2 * h][2] * scale, qreg[2 * h][3] * scale);
        u.z = pk2(qreg[2 * h + 1][0] * scale, qreg[2 * h + 1][1] * scale);
        u.w = pk2(qreg[2 * h + 1][2] * scale, qreg[2 * h + 1][3] * scale);
        bq[h] = __builtin_bit_cast(bf16x8, u);
    }
    __syncthreads();   // the only barrier

    // ========== S^T = K * Q^T : lane holds S^T[c*16+g*4+r][qbase+m] ================
    f32x4 acc[8];
    #pragma unroll
    for (int c = 0; c < 8; ++c) acc[c] = (f32x4){0.f, 0.f, 0.f, 0.f};
    __builtin_amdgcn_s_setprio(1);
    #pragma unroll
    for (int c = 0; c < 8; ++c) {
        const int krow = c * 16 + m;
        #pragma unroll
        for (int h = 0; h < 2; ++h) {
            const int byte = (krow * 128 + h * 64 + g * 16) ^ ((m & 7) << 4);
            const bf16x8 ak = *reinterpret_cast<const bf16x8*>(sKb + byte);
            acc[c] = __builtin_amdgcn_mfma_f32_16x16x32_bf16(ak, bq[h], acc[c], 0, 0, 0);
        }
    }
    __builtin_amdgcn_s_setprio(0);

    // ========== mask + exact softmax (exp2 domain) =================================
    const int qb = qbase + m;
    float mx = -3e38f;
    #pragma unroll
    for (int c = 0; c < 8; ++c) {
        #pragma unroll
        for (int r = 0; r < 4; ++r) {
            const int kk = c * 16 + g4 + r;
            const bool dead = (c >= 4) ? (kk - 64 > qb) : (bucket == 0);
            const float s = dead ? -1e30f : acc[c][r];
            acc[c][r] = s;
            mx = fmaxf(mx, s);
        }
    }
    mx = fmaxf(mx, __shfl_xor(mx, 16));
    mx = fmaxf(mx, __shfl_xor(mx, 32));
    float sum = 0.f;
    uint2 pb[8];
    #pragma unroll
    for (int c = 0; c < 8; ++c) {
        const float p0 = __builtin_amdgcn_exp2f(acc[c][0] - mx);
        const float p1 = __builtin_amdgcn_exp2f(acc[c][1] - mx);
        const float p2 = __builtin_amdgcn_exp2f(acc[c][2] - mx);
        const float p3 = __builtin_amdgcn_exp2f(acc[c][3] - mx);
        sum += (p0 + p1) + (p2 + p3);
        pb[c].x = pk2(p0, p1);
        pb[c].y = pk2(p2, p3);
    }
    sum += __shfl_xor(sum, 16);
    sum += __shfl_xor(sum, 32);
    const float rl = 1.0f / sum;

    // ========== P redistribution via shuffles (no LDS, no barrier) =================
    const int l0 = m + ((g & 1) << 5);
    const int l1 = l0 + 16;
    const bool hi2 = (g >> 1) != 0;
    bf16x8 bp[4];
    #pragma unroll
    for (int kt = 0; kt < 4; ++kt) {
        const unsigned a0x = __shfl(pb[2 * kt].x, l0),     a0y = __shfl(pb[2 * kt].y, l0);
        const unsigned a1x = __shfl(pb[2 * kt + 1].x, l0), a1y = __shfl(pb[2 * kt + 1].y, l0);
        const unsigned b0x = __shfl(pb[2 * kt].x, l1),     b0y = __shfl(pb[2 * kt].y, l1);
        const unsigned b1x = __shfl(pb[2 * kt + 1].x, l1), b1y = __shfl(pb[2 * kt + 1].y, l1);
        uint4 u;
        u.x = hi2 ? a1x : a0x;
        u.y = hi2 ? a1y : a0y;
        u.z = hi2 ? b1x : b0x;
        u.w = hi2 ? b1y : b0y;
        bp[kt] = __builtin_bit_cast(bf16x8, u);
    }

    // ========== O^T = V^T * P^T ====================================================
    f32x4 oacc[4];
    #pragma unroll
    for (int et = 0; et < 4; ++et) oacc[et] = (f32x4){0.f, 0.f, 0.f, 0.f};
    __builtin_amdgcn_s_setprio(1);
    #pragma unroll
    for (int et = 0; et < 4; ++et) {
        const int row = et * 16 + m;
        #pragma unroll
        for (int kt = 0; kt < 4; ++kt) {
            const int byte = (row * 256 + kt * 64 + g * 16) ^ swzV(row);
            const bf16x8 av = *reinterpret_cast<const bf16x8*>(sVb + byte);
            oacc[et] = __builtin_amdgcn_mfma_f32_16x16x32_bf16(av, bp[kt], oacc[et], 0, 0, 0);
        }
    }
    __builtin_amdgcn_s_setprio(0);

    // ========== epilogue: normalize, float4 stores =================================
    const int qrow = qbase + m;
    #pragma unroll
    for (int et = 0; et < 4; ++et) {
        f32x4 o = oacc[et];
        o[0] *= rl; o[1] *= rl; o[2] *= rl; o[3] *= rl;
        *reinterpret_cast<float4*>(out + qoff + qrow * HDIM + et * 16 + g4) =
            *reinterpret_cast<float4*>(&o);
    }
}

extern "C" void kernel_launch(void* const* d_in, const int* in_sizes, int n_in,
                              void* d_out, int out_size, void* d_ws, size_t ws_size,
                              hipStream_t stream) {
    const float* q = (const float*)d_in[0];
    const float* k = (const float*)d_in[1];
    const float* v = (const float*)d_in[2];
    float* out = (float*)d_out;
    const int bh = in_sizes[0] / (SEQ * HDIM);   // merged batch*heads = 64
    const int nblocks = bh * (SEQ / BKT);        // 4096
    hipLaunchKernelGGL(local_attn_kernel, dim3(nblocks), dim3(256), 0, stream,
                       q, k, v, out);
}